// Round 1
// baseline (301.431 us; speedup 1.0000x reference)
//
#include <hip/hip_runtime.h>
#include <hip/hip_bf16.h>
#include <cstdint>

// ---------------------------------------------------------------------------
// N=50000, E=600000, D_IN=256, H1=128, H2=64, DK=64, HEADS=2 (dk=32).
// R8: (1) Wom = Wo@[Wmu|Wvar] precomputed in prep_kv -> attn kernel drops the
// Wo GEMM and halves the mu/var GEMM K (no attended materialization).
// (2) spmm1 fused into attn kernel: each block gathers its 128 hidden rows
// directly into LDS Ap (hidden buffer + one dispatch eliminated); row bounds
// via one vector load + shfl per wave. (3) gcn1 A-staging uses
// v_cvt_pk_bf16_f32 (2 elems/instr) instead of ~5-op manual RNE.
// R7 retained: 1-row/wave spmm (final), merged scans, merged prep_kv.
// ---------------------------------------------------------------------------

typedef __attribute__((ext_vector_type(8))) short short8;
typedef __attribute__((ext_vector_type(4))) float f32x4;
typedef __attribute__((ext_vector_type(4))) unsigned short ushort4_t;

__device__ __forceinline__ unsigned short f2bf(float f) {
    unsigned int u = __builtin_bit_cast(unsigned int, f);
    u += 0x7fffu + ((u >> 16) & 1u);   // RNE
    return (unsigned short)(u >> 16);
}
__device__ __forceinline__ float bf2f(unsigned short v) {
    return __builtin_bit_cast(float, (unsigned int)v << 16);
}

// ---------------- CSR build --------------------------------------------------

__global__ void hist_kernel(const int* __restrict__ rows, int* __restrict__ cnt, int E) {
    int i = blockIdx.x * blockDim.x + threadIdx.x;
    if (i < E) atomicAdd(&cnt[rows[i]], 1);
}

__global__ void scan1_kernel(const int* __restrict__ cnt, int* __restrict__ excl,
                             int* __restrict__ bsum, int N) {
    __shared__ int sh[256];
    int t = threadIdx.x;
    int i = blockIdx.x * 256 + t;
    int v = (i < N) ? cnt[i] : 0;
    sh[t] = v;
    __syncthreads();
    for (int off = 1; off < 256; off <<= 1) {
        int x = (t >= off) ? sh[t - off] : 0;
        __syncthreads();
        sh[t] += x;
        __syncthreads();
    }
    if (i < N) excl[i] = sh[t] - v;
    if (t == 255) bsum[blockIdx.x] = sh[255];
}

__global__ void scan23_kernel(const int* __restrict__ excl, const int* __restrict__ bsum,
                              int* __restrict__ row_start, int* __restrict__ cursor,
                              int nb, int N, int E) {
    __shared__ int sh[256];
    int t = threadIdx.x;
    int v = (t < nb) ? bsum[t] : 0;
    sh[t] = v;
    __syncthreads();
    for (int off = 1; off < 256; off <<= 1) {
        int x = (t >= off) ? sh[t - off] : 0;
        __syncthreads();
        sh[t] += x;
        __syncthreads();
    }
    int boff = (blockIdx.x > 0) ? sh[blockIdx.x - 1] : 0;
    int i = blockIdx.x * 256 + t;
    if (i < N) {
        int w = excl[i] + boff;
        row_start[i] = w;
        cursor[i] = w;
    }
    if (i == 0) row_start[N] = E;
}

__global__ void scatter_kernel(const int* __restrict__ rows, const int* __restrict__ colsIn,
                               const float* __restrict__ valsIn, int* __restrict__ cursor,
                               int2* __restrict__ pack, int E) {
    int i = blockIdx.x * blockDim.x + threadIdx.x;
    if (i < E) {
        int r = rows[i];
        int p = atomicAdd(&cursor[r], 1);
        pack[p] = make_int2(colsIn[i], __float_as_int(valsIn[i]));
    }
}

// ---------------- weight prep + K/V projection + Wom (merged) ---------------
// blocks [0,160): transposes (WhT 32768 + WqT 8192 elements)
// blocks [160,224): K/V projection (2 keys per block)
// blocks [224,256): WomT[n][d] = bf16( sum_k Wo[d][k] * W(mu|var)[k][n&63] )

__global__ __launch_bounds__(256) void prep_kv_kernel(
    const float* __restrict__ Wh, const float* __restrict__ Wq,
    const float* __restrict__ cond,
    const float* __restrict__ Wk, const float* __restrict__ Wv,
    const float* __restrict__ Wo, const float* __restrict__ Wmu,
    const float* __restrict__ Wvar,
    unsigned short* __restrict__ WhT, unsigned short* __restrict__ WqT,
    unsigned short* __restrict__ Ktt, unsigned short* __restrict__ Vt,
    unsigned short* __restrict__ WomT)
{
    const int t = threadIdx.x;
    const int bid = blockIdx.x;
    if (bid < 160) {
        int idx = bid * 256 + t;
        if (idx < 32768) {
            int n = idx & 127, k = idx >> 7;                 // k<256
            WhT[n * 256 + k] = f2bf(Wh[k * 128 + n]);
        } else {
            int i = idx - 32768, n = i & 63, k = i >> 6;     // k<128
            WqT[n * 128 + k] = f2bf(Wq[k * 64 + n]);
        }
    } else if (bid < 224) {
        int b2 = bid - 160;                  // 0..63, 2 keys per block
        __shared__ float c[2][128];
        c[t >> 7][t & 127] = cond[b2 * 256 + t];
        __syncthreads();
        int j = b2 * 2 + (t >> 7);           // key index
        int tl = t & 127;
        const float* W = (tl < 64) ? Wk : Wv;
        int col = tl & 63;
        float acc = 0.f;
#pragma unroll 8
        for (int k = 0; k < 128; ++k) acc = fmaf(c[t >> 7][k], W[k * 64 + col], acc);
        int h = col >> 5, d = col & 31;
        if (tl < 64) Ktt[((size_t)h * 128 + j) * 32 + d] = f2bf(acc * 0.17677669529663687f);
        else         Vt[((size_t)h * 32 + d) * 128 + j] = f2bf(acc);
    } else {
        int wb = bid - 224;                  // 0..31
        __shared__ float WoTl[128 * 65];     // [k][d] padded
#pragma unroll
        for (int i = 0; i < 32; ++i) {
            int idx = t + 256 * i;           // 0..8191
            int d = idx >> 7, k = idx & 127;
            WoTl[k * 65 + d] = Wo[idx];      // Wo[d*128+k]
        }
        __syncthreads();
        int o = wb * 256 + t;                // 0..8191
        int d = o & 63, n = o >> 6;          // n: 0..127 (mu 0-63, var 64-127)
        const float* W = (n < 64) ? Wmu : Wvar;
        int j = n & 63;
        float acc = 0.f;
#pragma unroll 8
        for (int k = 0; k < 128; ++k) acc = fmaf(WoTl[k * 65 + d], W[k * 64 + j], acc);
        WomT[n * 64 + d] = f2bf(acc);
    }
}

// ---------------- GCN1 GEMM: support1 = lrelu(ns_emb @ Wh) ------------------

__global__ __launch_bounds__(256) void gcn1_gemm(
    const float* __restrict__ A, const unsigned short* __restrict__ BT,
    unsigned short* __restrict__ C, int M)
{
    __shared__ unsigned short As[128][72];
    __shared__ unsigned short Bs[128][72];

    const int tid = threadIdx.x;
    const int lane = tid & 63, wave = tid >> 6;
    const int wm = wave & 1, wn = wave >> 1;
    const int quad = lane >> 4, l16 = lane & 15;
    const int r0 = blockIdx.x * 128;

    f32x4 acc[4][4];
#pragma unroll
    for (int mt = 0; mt < 4; ++mt)
#pragma unroll
        for (int nt = 0; nt < 4; ++nt)
#pragma unroll
            for (int r = 0; r < 4; ++r) acc[mt][nt][r] = 0.f;

    for (int kc = 0; kc < 256; kc += 64) {
#pragma unroll
        for (int i = 0; i < 8; ++i) {
            int f = tid + 256 * i;
            int row = f >> 4, kq = (f & 15) << 2;
            int gr = r0 + row;
            if (gr >= M) gr = M - 1;
            float4 v = *reinterpret_cast<const float4*>(&A[(size_t)gr * 256 + kc + kq]);
            unsigned int lo, hi;
            asm("v_cvt_pk_bf16_f32 %0, %1, %2" : "=v"(lo) : "v"(v.x), "v"(v.y));
            asm("v_cvt_pk_bf16_f32 %0, %1, %2" : "=v"(hi) : "v"(v.z), "v"(v.w));
            *reinterpret_cast<uint2*>(&As[row][kq]) = make_uint2(lo, hi);
        }
#pragma unroll
        for (int i = 0; i < 4; ++i) {
            int f = tid + 256 * i;
            int n = f >> 3, k8 = (f & 7) << 3;
            *reinterpret_cast<short8*>(&Bs[n][k8]) =
                *reinterpret_cast<const short8*>(&BT[(size_t)n * 256 + kc + k8]);
        }
        __syncthreads();

#pragma unroll
        for (int ks = 0; ks < 2; ++ks) {
            const int koff = ks * 32 + quad * 8;
            short8 a[4], b[4];
#pragma unroll
            for (int mt = 0; mt < 4; ++mt)
                a[mt] = *reinterpret_cast<const short8*>(&As[wm * 64 + mt * 16 + l16][koff]);
#pragma unroll
            for (int nt = 0; nt < 4; ++nt)
                b[nt] = *reinterpret_cast<const short8*>(&Bs[wn * 64 + nt * 16 + l16][koff]);
#pragma unroll
            for (int mt = 0; mt < 4; ++mt)
#pragma unroll
                for (int nt = 0; nt < 4; ++nt)
                    acc[mt][nt] = __builtin_amdgcn_mfma_f32_16x16x32_bf16(
                        a[mt], b[nt], acc[mt][nt], 0, 0, 0);
        }
        __syncthreads();
    }

#pragma unroll
    for (int mt = 0; mt < 4; ++mt)
#pragma unroll
        for (int nt = 0; nt < 4; ++nt) {
            int gc = wn * 64 + nt * 16 + l16;
#pragma unroll
            for (int r = 0; r < 4; ++r) {
                int gr = r0 + wm * 64 + mt * 16 + quad * 4 + r;
                if (gr < M) {
                    float v = acc[mt][nt][r];
                    v = v > 0.f ? v : 0.01f * v;
                    C[(size_t)gr * 128 + gc] = f2bf(v);
                }
            }
        }
}

// ---------------- fused spmm1 + attention + muvar kernel --------------------
// Phase 0: hidden rows r0..r0+127 = lrelu(spmm(support1)) gathered directly
// into Ap (LDS). Then Q GEMM, per-head attention, ctx, and muvar = lrelu(
// ctx @ WomT) with K=64 (Wo folded into Wmu/Wvar on host-side prep).

__global__ __launch_bounds__(256) void attn_muvar_kernel(
    const unsigned short* __restrict__ support1, // [N,128] bf16
    const int* __restrict__ row_start,
    const int2* __restrict__ pack,
    const unsigned short* __restrict__ WqT,     // [64][128] bf16
    const unsigned short* __restrict__ Ktt,     // [2][128][32] bf16 (scaled)
    const unsigned short* __restrict__ Vt,      // [2][32][128] bf16
    const unsigned short* __restrict__ WomT,    // [128][64] bf16
    unsigned short* __restrict__ muvar,         // [N,128] bf16
    int M)
{
    __shared__ unsigned short Ap[128 * 136];
    __shared__ unsigned short Bp[10240];
    __shared__ unsigned short Cp[128 * 72];
    __shared__ float redm[2][128];
    __shared__ float reds[2][128];

    const int tid = threadIdx.x;
    const int lane = tid & 63, wave = tid >> 6;
    const int wm = wave & 1, wn = wave >> 1;
    const int quad = lane >> 4, l16 = lane & 15;
    const int r0 = blockIdx.x * 128;

    // stage WqT -> Bp early (independent of spmm; loads fly during gather)
#pragma unroll
    for (int i = 0; i < 4; ++i) {
        int f = tid + 256 * i;
        int n = f >> 4, k8 = (f & 15) << 3;
        *reinterpret_cast<short8*>(&Bp[n * 136 + k8]) =
            *reinterpret_cast<const short8*>(&WqT[(size_t)n * 128 + k8]);
    }

    // ---- Phase 0: fused SpMM -> Ap ----
    {
        const int fo = lane * 2;
        const int base = r0 + wave * 32;          // this wave's 32 rows
        const bool fast = (base + 32 <= M);
        int bnds = 0;
        if (fast && lane <= 32) bnds = row_start[base + lane];

        for (int it = 0; it < 32; ++it) {
            int row = wave * 32 + it;
            int s, e;
            if (fast) {
                s = __shfl(bnds, it, 64);
                e = __shfl(bnds, it + 1, 64);
            } else {
                int gr = r0 + row;
                if (gr >= M) gr = M - 1;
                s = __builtin_amdgcn_readfirstlane(row_start[gr]);
                e = __builtin_amdgcn_readfirstlane(row_start[gr + 1]);
            }

            float ax[8], ay[8];
#pragma unroll
            for (int k = 0; k < 8; ++k) { ax[k] = 0.f; ay[k] = 0.f; }

            int i = s;
            for (; i + 8 <= e; i += 8) {
                int2 p[8];
                unsigned int x[8];
#pragma unroll
                for (int k = 0; k < 8; ++k) p[k] = pack[i + k];
#pragma unroll
                for (int k = 0; k < 8; ++k)
                    x[k] = *reinterpret_cast<const unsigned int*>(&support1[(size_t)p[k].x * 128 + fo]);
#pragma unroll
                for (int k = 0; k < 8; ++k) {
                    float v = __int_as_float(p[k].y);
                    ax[k] = fmaf(v, bf2f((unsigned short)x[k]), ax[k]);
                    ay[k] = fmaf(v, bf2f((unsigned short)(x[k] >> 16)), ay[k]);
                }
            }
            if (i < e) {
                int2 p[8];
                unsigned int x[8];
#pragma unroll
                for (int k = 0; k < 8; ++k) {
                    int idx = i + k;
                    p[k] = pack[idx < e ? idx : e - 1];
                }
#pragma unroll
                for (int k = 0; k < 8; ++k)
                    x[k] = *reinterpret_cast<const unsigned int*>(&support1[(size_t)p[k].x * 128 + fo]);
#pragma unroll
                for (int k = 0; k < 8; ++k) {
                    float v = (i + k < e) ? __int_as_float(p[k].y) : 0.f;
                    ax[k] = fmaf(v, bf2f((unsigned short)x[k]), ax[k]);
                    ay[k] = fmaf(v, bf2f((unsigned short)(x[k] >> 16)), ay[k]);
                }
            }

            float ox = ((ax[0] + ax[1]) + (ax[2] + ax[3])) + ((ax[4] + ax[5]) + (ax[6] + ax[7]));
            float oy = ((ay[0] + ay[1]) + (ay[2] + ay[3])) + ((ay[4] + ay[5]) + (ay[6] + ay[7]));
            ox = ox > 0.f ? ox : 0.01f * ox;
            oy = oy > 0.f ? oy : 0.01f * oy;
            unsigned int w = (unsigned int)f2bf(ox) | ((unsigned int)f2bf(oy) << 16);
            *reinterpret_cast<unsigned int*>(&Ap[row * 136 + fo]) = w;
        }
    }
    __syncthreads();

    // ---- Q = hidden @ Wq -> Cp ----
    {
        f32x4 accq[4][2];
#pragma unroll
        for (int mt = 0; mt < 4; ++mt)
#pragma unroll
            for (int nt = 0; nt < 2; ++nt)
#pragma unroll
                for (int r = 0; r < 4; ++r) accq[mt][nt][r] = 0.f;
#pragma unroll
        for (int ks = 0; ks < 4; ++ks) {
            const int koff = ks * 32 + quad * 8;
            short8 a[4], b[2];
#pragma unroll
            for (int mt = 0; mt < 4; ++mt)
                a[mt] = *reinterpret_cast<const short8*>(&Ap[(wm * 64 + mt * 16 + l16) * 136 + koff]);
#pragma unroll
            for (int nt = 0; nt < 2; ++nt)
                b[nt] = *reinterpret_cast<const short8*>(&Bp[(wn * 32 + nt * 16 + l16) * 136 + koff]);
#pragma unroll
            for (int mt = 0; mt < 4; ++mt)
#pragma unroll
                for (int nt = 0; nt < 2; ++nt)
                    accq[mt][nt] = __builtin_amdgcn_mfma_f32_16x16x32_bf16(
                        a[mt], b[nt], accq[mt][nt], 0, 0, 0);
        }
#pragma unroll
        for (int mt = 0; mt < 4; ++mt)
#pragma unroll
            for (int nt = 0; nt < 2; ++nt) {
                int col = wn * 32 + nt * 16 + l16;
#pragma unroll
                for (int r = 0; r < 4; ++r) {
                    int row = wm * 64 + mt * 16 + quad * 4 + r;
                    Cp[row * 72 + col] = f2bf(accq[mt][nt][r]);
                }
            }
    }
    __syncthreads();

    for (int h = 0; h < 2; ++h) {
#pragma unroll
        for (int i = 0; i < 2; ++i) {
            int f = tid + 256 * i;
            int key = f >> 2, d8 = (f & 3) << 3;
            *reinterpret_cast<short8*>(&Bp[key * 40 + d8]) =
                *reinterpret_cast<const short8*>(&Ktt[((size_t)h * 128 + key) * 32 + d8]);
        }
#pragma unroll
        for (int i = 0; i < 2; ++i) {
            int f = tid + 256 * i;
            int d = f >> 4, k8 = (f & 15) << 3;
            *reinterpret_cast<short8*>(&Bp[5120 + d * 136 + k8]) =
                *reinterpret_cast<const short8*>(&Vt[((size_t)h * 32 + d) * 128 + k8]);
        }
        __syncthreads();

        f32x4 accl[4][4];
        {
            short8 a[4], b[4];
#pragma unroll
            for (int mt = 0; mt < 4; ++mt)
                a[mt] = *reinterpret_cast<const short8*>(&Cp[(wm * 64 + mt * 16 + l16) * 72 + h * 32 + quad * 8]);
#pragma unroll
            for (int nt = 0; nt < 4; ++nt)
                b[nt] = *reinterpret_cast<const short8*>(&Bp[(wn * 64 + nt * 16 + l16) * 40 + quad * 8]);
#pragma unroll
            for (int mt = 0; mt < 4; ++mt)
#pragma unroll
                for (int nt = 0; nt < 4; ++nt) {
                    f32x4 z; z[0] = 0.f; z[1] = 0.f; z[2] = 0.f; z[3] = 0.f;
                    accl[mt][nt] = __builtin_amdgcn_mfma_f32_16x16x32_bf16(a[mt], b[nt], z, 0, 0, 0);
                }
        }

#pragma unroll
        for (int mt = 0; mt < 4; ++mt)
#pragma unroll
            for (int r = 0; r < 4; ++r) {
                float mx = fmaxf(fmaxf(accl[mt][0][r], accl[mt][1][r]),
                                 fmaxf(accl[mt][2][r], accl[mt][3][r]));
#pragma unroll
                for (int off = 1; off < 16; off <<= 1)
                    mx = fmaxf(mx, __shfl_xor(mx, off, 64));
                if (l16 == 0) redm[wn][wm * 64 + mt * 16 + quad * 4 + r] = mx;
            }
        __syncthreads();
#pragma unroll
        for (int mt = 0; mt < 4; ++mt)
#pragma unroll
            for (int r = 0; r < 4; ++r) {
                int lr = wm * 64 + mt * 16 + quad * 4 + r;
                float fm = fmaxf(redm[0][lr], redm[1][lr]);
                float s = 0.f;
#pragma unroll
                for (int nt = 0; nt < 4; ++nt) {
                    float e = __expf(accl[mt][nt][r] - fm);
                    accl[mt][nt][r] = e;
                    s += e;
                }
#pragma unroll
                for (int off = 1; off < 16; off <<= 1)
                    s += __shfl_xor(s, off, 64);
                if (l16 == 0) reds[wn][lr] = s;
            }
        __syncthreads();
#pragma unroll
        for (int mt = 0; mt < 4; ++mt)
#pragma unroll
            for (int r = 0; r < 4; ++r) {
                int lr = wm * 64 + mt * 16 + quad * 4 + r;
                float inv = 1.0f / (reds[0][lr] + reds[1][lr]);
#pragma unroll
                for (int nt = 0; nt < 4; ++nt)
                    Ap[lr * 136 + wn * 64 + nt * 16 + l16] = f2bf(accl[mt][nt][r] * inv);
            }
        __syncthreads();

        {
            f32x4 accc[4];
#pragma unroll
            for (int mt = 0; mt < 4; ++mt)
#pragma unroll
                for (int r = 0; r < 4; ++r) accc[mt][r] = 0.f;
#pragma unroll
            for (int ks = 0; ks < 4; ++ks) {
                const int koff = ks * 32 + quad * 8;
                short8 a[4];
#pragma unroll
                for (int mt = 0; mt < 4; ++mt)
                    a[mt] = *reinterpret_cast<const short8*>(&Ap[(wm * 64 + mt * 16 + l16) * 136 + koff]);
                short8 bb = *reinterpret_cast<const short8*>(&Bp[5120 + (wn * 16 + l16) * 136 + koff]);
#pragma unroll
                for (int mt = 0; mt < 4; ++mt)
                    accc[mt] = __builtin_amdgcn_mfma_f32_16x16x32_bf16(a[mt], bb, accc[mt], 0, 0, 0);
            }
#pragma unroll
            for (int mt = 0; mt < 4; ++mt)
#pragma unroll
                for (int r = 0; r < 4; ++r) {
                    int row = wm * 64 + mt * 16 + quad * 4 + r;
                    Cp[row * 72 + h * 32 + wn * 16 + l16] = f2bf(accc[mt][r]);
                }
        }
        __syncthreads();
    }

    // ---- muvar = lrelu(ctx @ WomT), K=64 ----
#pragma unroll
    for (int i = 0; i < 4; ++i) {
        int f = tid + 256 * i;
        int n = f >> 3, k8 = (f & 7) << 3;
        *reinterpret_cast<short8*>(&Bp[n * 72 + k8]) =
            *reinterpret_cast<const short8*>(&WomT[(size_t)n * 64 + k8]);
    }
    __syncthreads();
    {
        f32x4 accf[4][4];
#pragma unroll
        for (int mt = 0; mt < 4; ++mt)
#pragma unroll
            for (int nt = 0; nt < 4; ++nt)
#pragma unroll
                for (int r = 0; r < 4; ++r) accf[mt][nt][r] = 0.f;
#pragma unroll
        for (int ks = 0; ks < 2; ++ks) {
            const int koff = ks * 32 + quad * 8;
            short8 a[4], b[4];
#pragma unroll
            for (int mt = 0; mt < 4; ++mt)
                a[mt] = *reinterpret_cast<const short8*>(&Cp[(wm * 64 + mt * 16 + l16) * 72 + koff]);
#pragma unroll
            for (int nt = 0; nt < 4; ++nt)
                b[nt] = *reinterpret_cast<const short8*>(&Bp[(wn * 64 + nt * 16 + l16) * 72 + koff]);
#pragma unroll
            for (int mt = 0; mt < 4; ++mt)
#pragma unroll
                for (int nt = 0; nt < 4; ++nt)
                    accf[mt][nt] = __builtin_amdgcn_mfma_f32_16x16x32_bf16(
                        a[mt], b[nt], accf[mt][nt], 0, 0, 0);
        }
#pragma unroll
        for (int mt = 0; mt < 4; ++mt)
#pragma unroll
            for (int nt = 0; nt < 4; ++nt) {
                int gc = wn * 64 + nt * 16 + l16;
#pragma unroll
                for (int r = 0; r < 4; ++r) {
                    int gr = r0 + wm * 64 + mt * 16 + quad * 4 + r;
                    if (gr < M) {
                        float v = accf[mt][nt][r];
                        v = v > 0.f ? v : 0.01f * v;
                        muvar[(size_t)gr * 128 + gc] = f2bf(v);
                    }
                }
            }
    }
}

// ---------------- SpMM: one row per wave, 8-deep gather pipeline ------------

template<bool SPLIT, typename OT>
__global__ __launch_bounds__(256) void spmm_kernel(
    const int* __restrict__ row_start, const int2* __restrict__ pack,
    const unsigned short* __restrict__ X,
    OT* __restrict__ out0, OT* __restrict__ out1, int N)
{
    const int wave = threadIdx.x >> 6, lane = threadIdx.x & 63;
    const int r = blockIdx.x * 4 + wave;
    if (r >= N) return;
    int s = __builtin_amdgcn_readfirstlane(row_start[r]);
    int e = __builtin_amdgcn_readfirstlane(row_start[r + 1]);
    const int fo = lane * 2;

    float ax[8], ay[8];
#pragma unroll
    for (int k = 0; k < 8; ++k) { ax[k] = 0.f; ay[k] = 0.f; }

    int i = s;
    for (; i + 8 <= e; i += 8) {
        int2 p[8];
        unsigned int x[8];
#pragma unroll
        for (int k = 0; k < 8; ++k) p[k] = pack[i + k];
#pragma unroll
        for (int k = 0; k < 8; ++k)
            x[k] = *reinterpret_cast<const unsigned int*>(&X[(size_t)p[k].x * 128 + fo]);
#pragma unroll
        for (int k = 0; k < 8; ++k) {
            float v = __int_as_float(p[k].y);
            ax[k] = fmaf(v, bf2f((unsigned short)x[k]), ax[k]);
            ay[k] = fmaf(v, bf2f((unsigned short)(x[k] >> 16)), ay[k]);
        }
    }
    if (i < e) {
        int2 p[8];
        unsigned int x[8];
#pragma unroll
        for (int k = 0; k < 8; ++k) {
            int idx = i + k;
            p[k] = pack[idx < e ? idx : e - 1];
        }
#pragma unroll
        for (int k = 0; k < 8; ++k)
            x[k] = *reinterpret_cast<const unsigned int*>(&X[(size_t)p[k].x * 128 + fo]);
#pragma unroll
        for (int k = 0; k < 8; ++k) {
            float v = (i + k < e) ? __int_as_float(p[k].y) : 0.f;
            ax[k] = fmaf(v, bf2f((unsigned short)x[k]), ax[k]);
            ay[k] = fmaf(v, bf2f((unsigned short)(x[k] >> 16)), ay[k]);
        }
    }

    float ox = ((ax[0] + ax[1]) + (ax[2] + ax[3])) + ((ax[4] + ax[5]) + (ax[6] + ax[7]));
    float oy = ((ay[0] + ay[1]) + (ay[2] + ay[3])) + ((ay[4] + ay[5]) + (ay[6] + ay[7]));
    ox = ox > 0.f ? ox : 0.01f * ox;
    oy = oy > 0.f ? oy : 0.01f * oy;

    if constexpr (!SPLIT) {
        unsigned int w = (unsigned int)f2bf(ox) | ((unsigned int)f2bf(oy) << 16);
        *reinterpret_cast<unsigned int*>(&out0[(size_t)r * 128 + fo]) = w;
    } else {
        if (lane < 32) {
            *reinterpret_cast<float2*>(&out0[(size_t)r * 64 + fo]) = make_float2(ox, oy);
        } else {
            *reinterpret_cast<float2*>(&out1[(size_t)r * 64 + (fo - 64)]) = make_float2(ox, oy);
        }
    }
}

// ---------------------------------------------------------------------------

extern "C" void kernel_launch(void* const* d_in, const int* in_sizes, int n_in,
                              void* d_out, int out_size, void* d_ws, size_t ws_size,
                              hipStream_t stream)
{
    const float* ns_emb   = (const float*)d_in[0];
    const int*   erows    = (const int*)d_in[1];
    const int*   ecols    = (const int*)d_in[2];
    const float* evals    = (const float*)d_in[3];
    const float* cond     = (const float*)d_in[4];
    const float* W_hidden = (const float*)d_in[5];
    const float* W_mu     = (const float*)d_in[6];
    const float* W_var    = (const float*)d_in[7];
    const float* Wq       = (const float*)d_in[8];
    const float* Wk       = (const float*)d_in[9];
    const float* Wv       = (const float*)d_in[10];
    const float* Wo       = (const float*)d_in[11];

    const int N = in_sizes[0] / 256;  // 50000
    const int E = in_sizes[1];        // 600000

    typedef unsigned short bf16;
    uint8_t* p = (uint8_t*)d_ws;
    auto alloc = [&](size_t bytes) {
        uint8_t* r = p;
        p += (bytes + 255) & ~(size_t)255;
        return r;
    };
    bf16* support1 = (bf16*)alloc(sizeof(bf16) * (size_t)N * 128);
    bf16* muvarb   = (bf16*)alloc(sizeof(bf16) * (size_t)N * 128);
    bf16* Ktt      = (bf16*)alloc(sizeof(bf16) * 2 * 128 * 32);
    bf16* Vt       = (bf16*)alloc(sizeof(bf16) * 2 * 32 * 128);
    bf16* WhT      = (bf16*)alloc(sizeof(bf16) * 128 * 256);
    bf16* WqT      = (bf16*)alloc(sizeof(bf16) * 64 * 128);
    bf16* WomT     = (bf16*)alloc(sizeof(bf16) * 128 * 64);
    int*  cnt      = (int*)alloc(sizeof(int) * N);
    int*  excl     = (int*)alloc(sizeof(int) * N);
    int*  bsum     = (int*)alloc(sizeof(int) * 256);
    int*  row_start= (int*)alloc(sizeof(int) * (N + 1));
    int*  cursor   = (int*)alloc(sizeof(int) * N);
    int2* pack     = (int2*)alloc(sizeof(int2) * E);

    // ---- CSR build ----
    hipMemsetAsync(cnt, 0, sizeof(int) * N, stream);
    hist_kernel<<<(E + 255) / 256, 256, 0, stream>>>(erows, cnt, E);
    int nb = (N + 255) / 256;   // 196
    scan1_kernel<<<nb, 256, 0, stream>>>(cnt, excl, bsum, N);
    scan23_kernel<<<nb, 256, 0, stream>>>(excl, bsum, row_start, cursor, nb, N, E);
    scatter_kernel<<<(E + 255) / 256, 256, 0, stream>>>(erows, ecols, evals, cursor, pack, E);

    // ---- weight prep + K/V + Wom (merged) ----
    prep_kv_kernel<<<256, 256, 0, stream>>>(W_hidden, Wq, cond, Wk, Wv,
                                            Wo, W_mu, W_var,
                                            WhT, WqT, Ktt, Vt, WomT);

    const int mb = (N + 127) / 128;   // 391
    const int sblocks = (N + 3) / 4;

    // ---- GCN1 ----
    gcn1_gemm<<<mb, 256, 0, stream>>>(ns_emb, WhT, support1, N);

    // ---- fused spmm1 + attention -> muvar ----
    attn_muvar_kernel<<<mb, 256, 0, stream>>>(support1, row_start, pack,
                                              WqT, Ktt, Vt, WomT, muvarb, N);

    // ---- final SpMM (split mu/var, fp32 out) ----
    float* out = (float*)d_out;
    spmm_kernel<true, float><<<sblocks, 256, 0, stream>>>(
        row_start, pack, muvarb, out, out + (size_t)N * 64, N);
}

// Round 2
// 268.824 us; speedup vs baseline: 1.1213x; 1.1213x over previous
//
#include <hip/hip_runtime.h>
#include <hip/hip_bf16.h>
#include <cstdint>

// ---------------------------------------------------------------------------
// N=50000, E=600000, D_IN=256, H1=128, H2=64, DK=64, HEADS=2 (dk=32).
// R9: fusion of spmm1 into attn REVERTED (R8 regression: 75KB LDS capped the
// latency-bound gather at 2 blocks/CU -> 90us). spmm1 standalone again.
// Kept from R8: Wom = Wo@[Wmu|Wvar] fold (attn has no Wo GEMM, muvar K=64),
// v_cvt_pk_bf16_f32 in gcn1 A-staging.
// New: attn BM 128->64 (782 blocks, ~3/CU fill, LDS 48KB -> 3 blocks/CU,
// per-block serial MFMA chain halved).
// ---------------------------------------------------------------------------

typedef __attribute__((ext_vector_type(8))) short short8;
typedef __attribute__((ext_vector_type(4))) float f32x4;
typedef __attribute__((ext_vector_type(4))) unsigned short ushort4_t;

__device__ __forceinline__ unsigned short f2bf(float f) {
    unsigned int u = __builtin_bit_cast(unsigned int, f);
    u += 0x7fffu + ((u >> 16) & 1u);   // RNE
    return (unsigned short)(u >> 16);
}
__device__ __forceinline__ float bf2f(unsigned short v) {
    return __builtin_bit_cast(float, (unsigned int)v << 16);
}

// ---------------- CSR build --------------------------------------------------

__global__ void hist_kernel(const int* __restrict__ rows, int* __restrict__ cnt, int E) {
    int i = blockIdx.x * blockDim.x + threadIdx.x;
    if (i < E) atomicAdd(&cnt[rows[i]], 1);
}

__global__ void scan1_kernel(const int* __restrict__ cnt, int* __restrict__ excl,
                             int* __restrict__ bsum, int N) {
    __shared__ int sh[256];
    int t = threadIdx.x;
    int i = blockIdx.x * 256 + t;
    int v = (i < N) ? cnt[i] : 0;
    sh[t] = v;
    __syncthreads();
    for (int off = 1; off < 256; off <<= 1) {
        int x = (t >= off) ? sh[t - off] : 0;
        __syncthreads();
        sh[t] += x;
        __syncthreads();
    }
    if (i < N) excl[i] = sh[t] - v;
    if (t == 255) bsum[blockIdx.x] = sh[255];
}

__global__ void scan23_kernel(const int* __restrict__ excl, const int* __restrict__ bsum,
                              int* __restrict__ row_start, int* __restrict__ cursor,
                              int nb, int N, int E) {
    __shared__ int sh[256];
    int t = threadIdx.x;
    int v = (t < nb) ? bsum[t] : 0;
    sh[t] = v;
    __syncthreads();
    for (int off = 1; off < 256; off <<= 1) {
        int x = (t >= off) ? sh[t - off] : 0;
        __syncthreads();
        sh[t] += x;
        __syncthreads();
    }
    int boff = (blockIdx.x > 0) ? sh[blockIdx.x - 1] : 0;
    int i = blockIdx.x * 256 + t;
    if (i < N) {
        int w = excl[i] + boff;
        row_start[i] = w;
        cursor[i] = w;
    }
    if (i == 0) row_start[N] = E;
}

__global__ void scatter_kernel(const int* __restrict__ rows, const int* __restrict__ colsIn,
                               const float* __restrict__ valsIn, int* __restrict__ cursor,
                               int2* __restrict__ pack, int E) {
    int i = blockIdx.x * blockDim.x + threadIdx.x;
    if (i < E) {
        int r = rows[i];
        int p = atomicAdd(&cursor[r], 1);
        pack[p] = make_int2(colsIn[i], __float_as_int(valsIn[i]));
    }
}

// ---------------- weight prep + K/V projection + Wom (merged) ---------------

__global__ __launch_bounds__(256) void prep_kv_kernel(
    const float* __restrict__ Wh, const float* __restrict__ Wq,
    const float* __restrict__ cond,
    const float* __restrict__ Wk, const float* __restrict__ Wv,
    const float* __restrict__ Wo, const float* __restrict__ Wmu,
    const float* __restrict__ Wvar,
    unsigned short* __restrict__ WhT, unsigned short* __restrict__ WqT,
    unsigned short* __restrict__ Ktt, unsigned short* __restrict__ Vt,
    unsigned short* __restrict__ WomT)
{
    const int t = threadIdx.x;
    const int bid = blockIdx.x;
    if (bid < 160) {
        int idx = bid * 256 + t;
        if (idx < 32768) {
            int n = idx & 127, k = idx >> 7;                 // k<256
            WhT[n * 256 + k] = f2bf(Wh[k * 128 + n]);
        } else {
            int i = idx - 32768, n = i & 63, k = i >> 6;     // k<128
            WqT[n * 128 + k] = f2bf(Wq[k * 64 + n]);
        }
    } else if (bid < 224) {
        int b2 = bid - 160;                  // 0..63, 2 keys per block
        __shared__ float c[2][128];
        c[t >> 7][t & 127] = cond[b2 * 256 + t];
        __syncthreads();
        int j = b2 * 2 + (t >> 7);           // key index
        int tl = t & 127;
        const float* W = (tl < 64) ? Wk : Wv;
        int col = tl & 63;
        float acc = 0.f;
#pragma unroll 8
        for (int k = 0; k < 128; ++k) acc = fmaf(c[t >> 7][k], W[k * 64 + col], acc);
        int h = col >> 5, d = col & 31;
        if (tl < 64) Ktt[((size_t)h * 128 + j) * 32 + d] = f2bf(acc * 0.17677669529663687f);
        else         Vt[((size_t)h * 32 + d) * 128 + j] = f2bf(acc);
    } else {
        int wb = bid - 224;                  // 0..31
        __shared__ float WoTl[128 * 65];     // [k][d] padded
#pragma unroll
        for (int i = 0; i < 32; ++i) {
            int idx = t + 256 * i;           // 0..8191
            int d = idx >> 7, k = idx & 127;
            WoTl[k * 65 + d] = Wo[idx];      // Wo[d*128+k]
        }
        __syncthreads();
        int o = wb * 256 + t;                // 0..8191
        int d = o & 63, n = o >> 6;          // n: 0..127 (mu 0-63, var 64-127)
        const float* W = (n < 64) ? Wmu : Wvar;
        int j = n & 63;
        float acc = 0.f;
#pragma unroll 8
        for (int k = 0; k < 128; ++k) acc = fmaf(WoTl[k * 65 + d], W[k * 64 + j], acc);
        WomT[n * 64 + d] = f2bf(acc);
    }
}

// ---------------- GCN1 GEMM: support1 = lrelu(ns_emb @ Wh) ------------------

__global__ __launch_bounds__(256) void gcn1_gemm(
    const float* __restrict__ A, const unsigned short* __restrict__ BT,
    unsigned short* __restrict__ C, int M)
{
    __shared__ unsigned short As[128][72];
    __shared__ unsigned short Bs[128][72];

    const int tid = threadIdx.x;
    const int lane = tid & 63, wave = tid >> 6;
    const int wm = wave & 1, wn = wave >> 1;
    const int quad = lane >> 4, l16 = lane & 15;
    const int r0 = blockIdx.x * 128;

    f32x4 acc[4][4];
#pragma unroll
    for (int mt = 0; mt < 4; ++mt)
#pragma unroll
        for (int nt = 0; nt < 4; ++nt)
#pragma unroll
            for (int r = 0; r < 4; ++r) acc[mt][nt][r] = 0.f;

    for (int kc = 0; kc < 256; kc += 64) {
#pragma unroll
        for (int i = 0; i < 8; ++i) {
            int f = tid + 256 * i;
            int row = f >> 4, kq = (f & 15) << 2;
            int gr = r0 + row;
            if (gr >= M) gr = M - 1;
            float4 v = *reinterpret_cast<const float4*>(&A[(size_t)gr * 256 + kc + kq]);
            unsigned int lo, hi;
            asm("v_cvt_pk_bf16_f32 %0, %1, %2" : "=v"(lo) : "v"(v.x), "v"(v.y));
            asm("v_cvt_pk_bf16_f32 %0, %1, %2" : "=v"(hi) : "v"(v.z), "v"(v.w));
            *reinterpret_cast<uint2*>(&As[row][kq]) = make_uint2(lo, hi);
        }
#pragma unroll
        for (int i = 0; i < 4; ++i) {
            int f = tid + 256 * i;
            int n = f >> 3, k8 = (f & 7) << 3;
            *reinterpret_cast<short8*>(&Bs[n][k8]) =
                *reinterpret_cast<const short8*>(&BT[(size_t)n * 256 + kc + k8]);
        }
        __syncthreads();

#pragma unroll
        for (int ks = 0; ks < 2; ++ks) {
            const int koff = ks * 32 + quad * 8;
            short8 a[4], b[4];
#pragma unroll
            for (int mt = 0; mt < 4; ++mt)
                a[mt] = *reinterpret_cast<const short8*>(&As[wm * 64 + mt * 16 + l16][koff]);
#pragma unroll
            for (int nt = 0; nt < 4; ++nt)
                b[nt] = *reinterpret_cast<const short8*>(&Bs[wn * 64 + nt * 16 + l16][koff]);
#pragma unroll
            for (int mt = 0; mt < 4; ++mt)
#pragma unroll
                for (int nt = 0; nt < 4; ++nt)
                    acc[mt][nt] = __builtin_amdgcn_mfma_f32_16x16x32_bf16(
                        a[mt], b[nt], acc[mt][nt], 0, 0, 0);
        }
        __syncthreads();
    }

#pragma unroll
    for (int mt = 0; mt < 4; ++mt)
#pragma unroll
        for (int nt = 0; nt < 4; ++nt) {
            int gc = wn * 64 + nt * 16 + l16;
#pragma unroll
            for (int r = 0; r < 4; ++r) {
                int gr = r0 + wm * 64 + mt * 16 + quad * 4 + r;
                if (gr < M) {
                    float v = acc[mt][nt][r];
                    v = v > 0.f ? v : 0.01f * v;
                    C[(size_t)gr * 128 + gc] = f2bf(v);
                }
            }
        }
}

// ---------------- attention + muvar kernel (BM=64) --------------------------
// Per block: 64 rows of hidden. Q = hidden@Wq; per-head logits/softmax/ctx;
// muvar = lrelu(ctx @ WomT) with K=64 (Wo folded). 4 waves in 2x2 grid,
// each wave owns 32 rows x (32|64) cols per phase.

__global__ __launch_bounds__(256) void attn_muvar_kernel(
    const unsigned short* __restrict__ hidden,  // [N,128] bf16
    const unsigned short* __restrict__ WqT,     // [64][128] bf16
    const unsigned short* __restrict__ Ktt,     // [2][128][32] bf16 (scaled)
    const unsigned short* __restrict__ Vt,      // [2][32][128] bf16
    const unsigned short* __restrict__ WomT,    // [128][64] bf16
    unsigned short* __restrict__ muvar,         // [N,128] bf16
    int M)
{
    __shared__ unsigned short Ap[64 * 136];
    __shared__ unsigned short Bp[10240];
    __shared__ unsigned short Cp[64 * 72];
    __shared__ float redm[2][64];
    __shared__ float reds[2][64];

    const int tid = threadIdx.x;
    const int lane = tid & 63, wave = tid >> 6;
    const int wm = wave & 1, wn = wave >> 1;
    const int quad = lane >> 4, l16 = lane & 15;
    const int r0 = blockIdx.x * 64;

    // stage hidden rows -> Ap, WqT -> Bp
#pragma unroll
    for (int i = 0; i < 4; ++i) {
        int f = tid + 256 * i;
        int row = f >> 4, k8 = (f & 15) << 3;
        int gr = r0 + row;
        if (gr >= M) gr = M - 1;
        *reinterpret_cast<short8*>(&Ap[row * 136 + k8]) =
            *reinterpret_cast<const short8*>(&hidden[(size_t)gr * 128 + k8]);
    }
#pragma unroll
    for (int i = 0; i < 4; ++i) {
        int f = tid + 256 * i;
        int n = f >> 4, k8 = (f & 15) << 3;
        *reinterpret_cast<short8*>(&Bp[n * 136 + k8]) =
            *reinterpret_cast<const short8*>(&WqT[(size_t)n * 128 + k8]);
    }
    __syncthreads();

    // ---- Q = hidden @ Wq -> Cp ----
    {
        f32x4 accq[2][2];
#pragma unroll
        for (int mt = 0; mt < 2; ++mt)
#pragma unroll
            for (int nt = 0; nt < 2; ++nt)
#pragma unroll
                for (int r = 0; r < 4; ++r) accq[mt][nt][r] = 0.f;
#pragma unroll
        for (int ks = 0; ks < 4; ++ks) {
            const int koff = ks * 32 + quad * 8;
            short8 a[2], b[2];
#pragma unroll
            for (int mt = 0; mt < 2; ++mt)
                a[mt] = *reinterpret_cast<const short8*>(&Ap[(wm * 32 + mt * 16 + l16) * 136 + koff]);
#pragma unroll
            for (int nt = 0; nt < 2; ++nt)
                b[nt] = *reinterpret_cast<const short8*>(&Bp[(wn * 32 + nt * 16 + l16) * 136 + koff]);
#pragma unroll
            for (int mt = 0; mt < 2; ++mt)
#pragma unroll
                for (int nt = 0; nt < 2; ++nt)
                    accq[mt][nt] = __builtin_amdgcn_mfma_f32_16x16x32_bf16(
                        a[mt], b[nt], accq[mt][nt], 0, 0, 0);
        }
#pragma unroll
        for (int mt = 0; mt < 2; ++mt)
#pragma unroll
            for (int nt = 0; nt < 2; ++nt) {
                int col = wn * 32 + nt * 16 + l16;
#pragma unroll
                for (int r = 0; r < 4; ++r) {
                    int row = wm * 32 + mt * 16 + quad * 4 + r;
                    Cp[row * 72 + col] = f2bf(accq[mt][nt][r]);
                }
            }
    }
    __syncthreads();

    for (int h = 0; h < 2; ++h) {
        // stage K (128 keys x 32 d) and V (32 d x 128 keys)
#pragma unroll
        for (int i = 0; i < 2; ++i) {
            int f = tid + 256 * i;
            int key = f >> 2, d8 = (f & 3) << 3;
            *reinterpret_cast<short8*>(&Bp[key * 40 + d8]) =
                *reinterpret_cast<const short8*>(&Ktt[((size_t)h * 128 + key) * 32 + d8]);
        }
#pragma unroll
        for (int i = 0; i < 2; ++i) {
            int f = tid + 256 * i;
            int d = f >> 4, k8 = (f & 15) << 3;
            *reinterpret_cast<short8*>(&Bp[5120 + d * 136 + k8]) =
                *reinterpret_cast<const short8*>(&Vt[((size_t)h * 32 + d) * 128 + k8]);
        }
        __syncthreads();

        f32x4 accl[2][4];
        {
            short8 a[2], b[4];
#pragma unroll
            for (int mt = 0; mt < 2; ++mt)
                a[mt] = *reinterpret_cast<const short8*>(&Cp[(wm * 32 + mt * 16 + l16) * 72 + h * 32 + quad * 8]);
#pragma unroll
            for (int nt = 0; nt < 4; ++nt)
                b[nt] = *reinterpret_cast<const short8*>(&Bp[(wn * 64 + nt * 16 + l16) * 40 + quad * 8]);
#pragma unroll
            for (int mt = 0; mt < 2; ++mt)
#pragma unroll
                for (int nt = 0; nt < 4; ++nt) {
                    f32x4 z; z[0] = 0.f; z[1] = 0.f; z[2] = 0.f; z[3] = 0.f;
                    accl[mt][nt] = __builtin_amdgcn_mfma_f32_16x16x32_bf16(a[mt], b[nt], z, 0, 0, 0);
                }
        }

#pragma unroll
        for (int mt = 0; mt < 2; ++mt)
#pragma unroll
            for (int r = 0; r < 4; ++r) {
                float mx = fmaxf(fmaxf(accl[mt][0][r], accl[mt][1][r]),
                                 fmaxf(accl[mt][2][r], accl[mt][3][r]));
#pragma unroll
                for (int off = 1; off < 16; off <<= 1)
                    mx = fmaxf(mx, __shfl_xor(mx, off, 64));
                if (l16 == 0) redm[wn][wm * 32 + mt * 16 + quad * 4 + r] = mx;
            }
        __syncthreads();
#pragma unroll
        for (int mt = 0; mt < 2; ++mt)
#pragma unroll
            for (int r = 0; r < 4; ++r) {
                int lr = wm * 32 + mt * 16 + quad * 4 + r;
                float fm = fmaxf(redm[0][lr], redm[1][lr]);
                float s = 0.f;
#pragma unroll
                for (int nt = 0; nt < 4; ++nt) {
                    float e = __expf(accl[mt][nt][r] - fm);
                    accl[mt][nt][r] = e;
                    s += e;
                }
#pragma unroll
                for (int off = 1; off < 16; off <<= 1)
                    s += __shfl_xor(s, off, 64);
                if (l16 == 0) reds[wn][lr] = s;
            }
        __syncthreads();
#pragma unroll
        for (int mt = 0; mt < 2; ++mt)
#pragma unroll
            for (int r = 0; r < 4; ++r) {
                int lr = wm * 32 + mt * 16 + quad * 4 + r;
                float inv = 1.0f / (reds[0][lr] + reds[1][lr]);
#pragma unroll
                for (int nt = 0; nt < 4; ++nt)
                    Ap[lr * 136 + wn * 64 + nt * 16 + l16] = f2bf(accl[mt][nt][r] * inv);
            }
        __syncthreads();

        // ctx = P @ V^T -> Cp
        {
            f32x4 accc[2];
#pragma unroll
            for (int mt = 0; mt < 2; ++mt)
#pragma unroll
                for (int r = 0; r < 4; ++r) accc[mt][r] = 0.f;
#pragma unroll
            for (int ks = 0; ks < 4; ++ks) {
                const int koff = ks * 32 + quad * 8;
                short8 a[2];
#pragma unroll
                for (int mt = 0; mt < 2; ++mt)
                    a[mt] = *reinterpret_cast<const short8*>(&Ap[(wm * 32 + mt * 16 + l16) * 136 + koff]);
                short8 bb = *reinterpret_cast<const short8*>(&Bp[5120 + (wn * 16 + l16) * 136 + koff]);
#pragma unroll
                for (int mt = 0; mt < 2; ++mt)
                    accc[mt] = __builtin_amdgcn_mfma_f32_16x16x32_bf16(a[mt], bb, accc[mt], 0, 0, 0);
            }
#pragma unroll
            for (int mt = 0; mt < 2; ++mt)
#pragma unroll
                for (int r = 0; r < 4; ++r) {
                    int row = wm * 32 + mt * 16 + quad * 4 + r;
                    Cp[row * 72 + h * 32 + wn * 16 + l16] = f2bf(accc[mt][r]);
                }
        }
        __syncthreads();
    }

    // ---- muvar = lrelu(ctx @ WomT), K=64 ----
#pragma unroll
    for (int i = 0; i < 4; ++i) {
        int f = tid + 256 * i;
        int n = f >> 3, k8 = (f & 7) << 3;
        *reinterpret_cast<short8*>(&Bp[n * 72 + k8]) =
            *reinterpret_cast<const short8*>(&WomT[(size_t)n * 64 + k8]);
    }
    __syncthreads();
    {
        f32x4 accf[2][4];
#pragma unroll
        for (int mt = 0; mt < 2; ++mt)
#pragma unroll
            for (int nt = 0; nt < 4; ++nt)
#pragma unroll
                for (int r = 0; r < 4; ++r) accf[mt][nt][r] = 0.f;
#pragma unroll
        for (int ks = 0; ks < 2; ++ks) {
            const int koff = ks * 32 + quad * 8;
            short8 a[2], b[4];
#pragma unroll
            for (int mt = 0; mt < 2; ++mt)
                a[mt] = *reinterpret_cast<const short8*>(&Cp[(wm * 32 + mt * 16 + l16) * 72 + koff]);
#pragma unroll
            for (int nt = 0; nt < 4; ++nt)
                b[nt] = *reinterpret_cast<const short8*>(&Bp[(wn * 64 + nt * 16 + l16) * 72 + koff]);
#pragma unroll
            for (int mt = 0; mt < 2; ++mt)
#pragma unroll
                for (int nt = 0; nt < 4; ++nt)
                    accf[mt][nt] = __builtin_amdgcn_mfma_f32_16x16x32_bf16(
                        a[mt], b[nt], accf[mt][nt], 0, 0, 0);
        }
#pragma unroll
        for (int mt = 0; mt < 2; ++mt)
#pragma unroll
            for (int nt = 0; nt < 4; ++nt) {
                int gc = wn * 64 + nt * 16 + l16;
#pragma unroll
                for (int r = 0; r < 4; ++r) {
                    int gr = r0 + wm * 32 + mt * 16 + quad * 4 + r;
                    if (gr < M) {
                        float v = accf[mt][nt][r];
                        v = v > 0.f ? v : 0.01f * v;
                        muvar[(size_t)gr * 128 + gc] = f2bf(v);
                    }
                }
            }
    }
}

// ---------------- SpMM: one row per wave, 8-deep gather pipeline ------------

template<bool SPLIT, typename OT>
__global__ __launch_bounds__(256) void spmm_kernel(
    const int* __restrict__ row_start, const int2* __restrict__ pack,
    const unsigned short* __restrict__ X,
    OT* __restrict__ out0, OT* __restrict__ out1, int N)
{
    const int wave = threadIdx.x >> 6, lane = threadIdx.x & 63;
    const int r = blockIdx.x * 4 + wave;
    if (r >= N) return;
    int s = __builtin_amdgcn_readfirstlane(row_start[r]);
    int e = __builtin_amdgcn_readfirstlane(row_start[r + 1]);
    const int fo = lane * 2;

    float ax[8], ay[8];
#pragma unroll
    for (int k = 0; k < 8; ++k) { ax[k] = 0.f; ay[k] = 0.f; }

    int i = s;
    for (; i + 8 <= e; i += 8) {
        int2 p[8];
        unsigned int x[8];
#pragma unroll
        for (int k = 0; k < 8; ++k) p[k] = pack[i + k];
#pragma unroll
        for (int k = 0; k < 8; ++k)
            x[k] = *reinterpret_cast<const unsigned int*>(&X[(size_t)p[k].x * 128 + fo]);
#pragma unroll
        for (int k = 0; k < 8; ++k) {
            float v = __int_as_float(p[k].y);
            ax[k] = fmaf(v, bf2f((unsigned short)x[k]), ax[k]);
            ay[k] = fmaf(v, bf2f((unsigned short)(x[k] >> 16)), ay[k]);
        }
    }
    if (i < e) {
        int2 p[8];
        unsigned int x[8];
#pragma unroll
        for (int k = 0; k < 8; ++k) {
            int idx = i + k;
            p[k] = pack[idx < e ? idx : e - 1];
        }
#pragma unroll
        for (int k = 0; k < 8; ++k)
            x[k] = *reinterpret_cast<const unsigned int*>(&X[(size_t)p[k].x * 128 + fo]);
#pragma unroll
        for (int k = 0; k < 8; ++k) {
            float v = (i + k < e) ? __int_as_float(p[k].y) : 0.f;
            ax[k] = fmaf(v, bf2f((unsigned short)x[k]), ax[k]);
            ay[k] = fmaf(v, bf2f((unsigned short)(x[k] >> 16)), ay[k]);
        }
    }

    float ox = ((ax[0] + ax[1]) + (ax[2] + ax[3])) + ((ax[4] + ax[5]) + (ax[6] + ax[7]));
    float oy = ((ay[0] + ay[1]) + (ay[2] + ay[3])) + ((ay[4] + ay[5]) + (ay[6] + ay[7]));
    ox = ox > 0.f ? ox : 0.01f * ox;
    oy = oy > 0.f ? oy : 0.01f * oy;

    if constexpr (!SPLIT) {
        unsigned int w = (unsigned int)f2bf(ox) | ((unsigned int)f2bf(oy) << 16);
        *reinterpret_cast<unsigned int*>(&out0[(size_t)r * 128 + fo]) = w;
    } else {
        if (lane < 32) {
            *reinterpret_cast<float2*>(&out0[(size_t)r * 64 + fo]) = make_float2(ox, oy);
        } else {
            *reinterpret_cast<float2*>(&out1[(size_t)r * 64 + (fo - 64)]) = make_float2(ox, oy);
        }
    }
}

// ---------------------------------------------------------------------------

extern "C" void kernel_launch(void* const* d_in, const int* in_sizes, int n_in,
                              void* d_out, int out_size, void* d_ws, size_t ws_size,
                              hipStream_t stream)
{
    const float* ns_emb   = (const float*)d_in[0];
    const int*   erows    = (const int*)d_in[1];
    const int*   ecols    = (const int*)d_in[2];
    const float* evals    = (const float*)d_in[3];
    const float* cond     = (const float*)d_in[4];
    const float* W_hidden = (const float*)d_in[5];
    const float* W_mu     = (const float*)d_in[6];
    const float* W_var    = (const float*)d_in[7];
    const float* Wq       = (const float*)d_in[8];
    const float* Wk       = (const float*)d_in[9];
    const float* Wv       = (const float*)d_in[10];
    const float* Wo       = (const float*)d_in[11];

    const int N = in_sizes[0] / 256;  // 50000
    const int E = in_sizes[1];        // 600000

    typedef unsigned short bf16;
    uint8_t* p = (uint8_t*)d_ws;
    auto alloc = [&](size_t bytes) {
        uint8_t* r = p;
        p += (bytes + 255) & ~(size_t)255;
        return r;
    };
    bf16* support1 = (bf16*)alloc(sizeof(bf16) * (size_t)N * 128);
    bf16* hidden   = (bf16*)alloc(sizeof(bf16) * (size_t)N * 128);
    bf16* muvarb   = (bf16*)alloc(sizeof(bf16) * (size_t)N * 128);
    bf16* Ktt      = (bf16*)alloc(sizeof(bf16) * 2 * 128 * 32);
    bf16* Vt       = (bf16*)alloc(sizeof(bf16) * 2 * 32 * 128);
    bf16* WhT      = (bf16*)alloc(sizeof(bf16) * 128 * 256);
    bf16* WqT      = (bf16*)alloc(sizeof(bf16) * 64 * 128);
    bf16* WomT     = (bf16*)alloc(sizeof(bf16) * 128 * 64);
    int*  cnt      = (int*)alloc(sizeof(int) * N);
    int*  excl     = (int*)alloc(sizeof(int) * N);
    int*  bsum     = (int*)alloc(sizeof(int) * 256);
    int*  row_start= (int*)alloc(sizeof(int) * (N + 1));
    int*  cursor   = (int*)alloc(sizeof(int) * N);
    int2* pack     = (int2*)alloc(sizeof(int2) * E);

    // ---- CSR build ----
    hipMemsetAsync(cnt, 0, sizeof(int) * N, stream);
    hist_kernel<<<(E + 255) / 256, 256, 0, stream>>>(erows, cnt, E);
    int nb = (N + 255) / 256;   // 196
    scan1_kernel<<<nb, 256, 0, stream>>>(cnt, excl, bsum, N);
    scan23_kernel<<<nb, 256, 0, stream>>>(excl, bsum, row_start, cursor, nb, N, E);
    scatter_kernel<<<(E + 255) / 256, 256, 0, stream>>>(erows, ecols, evals, cursor, pack, E);

    // ---- weight prep + K/V + Wom (merged) ----
    prep_kv_kernel<<<256, 256, 0, stream>>>(W_hidden, Wq, cond, Wk, Wv,
                                            Wo, W_mu, W_var,
                                            WhT, WqT, Ktt, Vt, WomT);

    const int mb128 = (N + 127) / 128;  // 391
    const int mb64  = (N + 63) / 64;    // 782
    const int sblocks = (N + 3) / 4;

    // ---- GCN1 ----
    gcn1_gemm<<<mb128, 256, 0, stream>>>(ns_emb, WhT, support1, N);
    spmm_kernel<false, bf16><<<sblocks, 256, 0, stream>>>(
        row_start, pack, support1, hidden, nullptr, N);

    // ---- attention -> muvar ----
    attn_muvar_kernel<<<mb64, 256, 0, stream>>>(hidden, WqT, Ktt, Vt,
                                                WomT, muvarb, N);

    // ---- final SpMM (split mu/var, fp32 out) ----
    float* out = (float*)d_out;
    spmm_kernel<true, float><<<sblocks, 256, 0, stream>>>(
        row_start, pack, muvarb, out, out + (size_t)N * 64, N);
}